// Round 1
// baseline (441.988 us; speedup 1.0000x reference)
//
#include <hip/hip_runtime.h>

#define B_   2
#define NWQ  75
#define PQ   196
#define D_   64
#define WAY  5
#define SHOT 5
#define SSUP (SHOT * PQ)   // 980 support patches per (b, way)

// One block per (b, q, w). Thread p (< 196) computes 980 dot products of its
// query row against all support rows of class w, keeps top-3 branchlessly,
// then block-reduces the sum of top-3 over p.
__global__ __launch_bounds__(256)
void lpc_kernel(const float* __restrict__ qfea,
                const float* __restrict__ sfea,
                float* __restrict__ out) {
    const int blk = blockIdx.x;            // = (b*NWQ + q)*WAY + w  (matches out layout)
    const int w  = blk % WAY;
    const int qi = (blk / WAY) % NWQ;
    const int b  = blk / (WAY * NWQ);
    const int p  = threadIdx.x;

    float sum3 = 0.0f;

    if (p < PQ) {
        // ---- load this thread's query row (64 floats) into registers ----
        float qreg[D_];
        const float4* q4 = reinterpret_cast<const float4*>(
            qfea + (((size_t)b * NWQ + qi) * PQ + p) * D_);
        #pragma unroll
        for (int i = 0; i < D_ / 4; ++i) {
            float4 v = q4[i];
            qreg[4 * i + 0] = v.x;
            qreg[4 * i + 1] = v.y;
            qreg[4 * i + 2] = v.z;
            qreg[4 * i + 3] = v.w;
        }

        // ---- scan all 980 support rows (wave-uniform address -> broadcast) ----
        const float* sbase = sfea + ((size_t)b * WAY + w) * SSUP * D_;
        float t0 = -INFINITY, t1 = -INFINITY, t2 = -INFINITY;

        for (int s = 0; s < SSUP; ++s) {
            const float4* s4 = reinterpret_cast<const float4*>(sbase + (size_t)s * D_);
            float a0 = 0.f, a1 = 0.f, a2 = 0.f, a3 = 0.f;
            #pragma unroll
            for (int i = 0; i < D_ / 4; ++i) {
                float4 v = s4[i];
                a0 = fmaf(qreg[4 * i + 0], v.x, a0);
                a1 = fmaf(qreg[4 * i + 1], v.y, a1);
                a2 = fmaf(qreg[4 * i + 2], v.z, a2);
                a3 = fmaf(qreg[4 * i + 3], v.w, a3);
            }
            float dot = (a0 + a1) + (a2 + a3);

            // branchless top-3 insertion (t0 >= t1 >= t2)
            float m0 = fminf(dot, t0);   t0 = fmaxf(dot, t0);
            float m1 = fminf(m0, t1);    t1 = fmaxf(m0, t1);
            t2 = fmaxf(m1, t2);
        }
        sum3 = t0 + t1 + t2;
    }

    // ---- block reduction over the 196 active threads ----
    __shared__ float red[256];
    red[threadIdx.x] = sum3;
    __syncthreads();
    #pragma unroll
    for (int off = 128; off > 0; off >>= 1) {
        if (threadIdx.x < off) red[threadIdx.x] += red[threadIdx.x + off];
        __syncthreads();
    }
    if (threadIdx.x == 0) {
        out[blk] = red[0] * (1.0f / (PQ * 3.0f));   // mean over 196 patches x k=3
    }
}

extern "C" void kernel_launch(void* const* d_in, const int* in_sizes, int n_in,
                              void* d_out, int out_size, void* d_ws, size_t ws_size,
                              hipStream_t stream) {
    const float* qfea = (const float*)d_in[0];  // [2,75,196,64]
    const float* sfea = (const float*)d_in[1];  // [2,5,5,196,64]
    float* out = (float*)d_out;                 // [150,5]

    const int nblk = B_ * NWQ * WAY;            // 750
    lpc_kernel<<<nblk, 256, 0, stream>>>(qfea, sfea, out);
}

// Round 2
// 62.927 us; speedup vs baseline: 7.0238x; 7.0238x over previous
//
#include <hip/hip_runtime.h>

#define B_    2
#define NWQ   75
#define PQ    196
#define D_    64
#define WAY   5
#define SHOT  5
#define SSUP  (SHOT * PQ)          // 980 support patches per (b, way)
#define STILES ((SSUP + 15) / 16)  // 62 support tiles of 16
#define QTILES ((PQ + 15) / 16)    // 13 query tiles of 16

typedef __attribute__((ext_vector_type(8))) short short8;   // 8 bf16 = 4 VGPR
typedef __attribute__((ext_vector_type(4))) float f32x4;

// ---------------- fp32 -> bf16 (RTNE) conversion pre-pass ----------------
__device__ __forceinline__ ushort f2bf(float f) {
    uint u = __builtin_bit_cast(uint, f);
    u = (u + 0x7FFFu + ((u >> 16) & 1u)) >> 16;
    return (ushort)u;
}

__global__ void cvt_kernel(const float* __restrict__ in, ushort* __restrict__ out, int n4) {
    int i = blockIdx.x * blockDim.x + threadIdx.x;
    if (i < n4) {
        float4 v = ((const float4*)in)[i];
        ushort4 o;
        o.x = f2bf(v.x); o.y = f2bf(v.y); o.z = f2bf(v.z); o.w = f2bf(v.w);
        ((ushort4*)out)[i] = o;
    }
}

// ---------------- MFMA main kernel ----------------
// Block = (b, qi, w). 8 waves; wave handles query-tiles {wid, wid+8} (each 16
// query patches). Loop over 62 support tiles: stage S-tile [16][64]bf16 into
// XOR-swizzled double-buffered LDS, mfma(A=S_tile, B=Q_tile) so C holds
// col=query (lane&15), row=support ((lane>>4)*4+reg); insert the 4 lane-local
// support values into a running branchless top-3; merge across lane-groups at
// the end via shfl_xor(16|32); block-reduce the per-query sums.
__global__ __launch_bounds__(512)
void lpc_mfma(const ushort* __restrict__ Qb, const ushort* __restrict__ Sb,
              float* __restrict__ out) {
    const int blk  = blockIdx.x;            // (b*NWQ + qi)*WAY + w == out index
    const int w    = blk % WAY;
    const int qi   = (blk / WAY) % NWQ;
    const int b    = blk / (WAY * NWQ);
    const int tid  = threadIdx.x;
    const int wid  = tid >> 6;              // 0..7
    const int lane = tid & 63;
    const int lr   = lane & 15;             // A-row within tile / query col
    const int lg   = lane >> 4;             // lane group 0..3

    __shared__ ushort lds[2][1024];         // 2 x 2KB swizzled S tiles
    __shared__ float  red[8];

    const ushort* Sc = Sb + (size_t)(b * WAY + w) * SSUP * D_;
    const ushort* Qc = Qb + (size_t)(b * NWQ + qi) * PQ * D_;

    // ---- preload this wave's query fragments (B operand) ----
    short8 bq[2][2];
    bool   qtv[2], qv[2];
    #pragma unroll
    for (int i = 0; i < 2; ++i) {
        int qt = wid + 8 * i;
        qtv[i] = (qt < QTILES);
        int p  = qt * 16 + lr;
        qv[i]  = qtv[i] && (p < PQ);
        int pc = qv[i] ? p : 0;             // clamp; masked at reduction
        const ushort* qrow = Qc + (size_t)pc * D_;
        if (qtv[i]) {
            bq[i][0] = *(const short8*)(qrow + 0  + lg * 8);
            bq[i][1] = *(const short8*)(qrow + 32 + lg * 8);
        } else {
            bq[i][0] = short8{0,0,0,0,0,0,0,0};
            bq[i][1] = short8{0,0,0,0,0,0,0,0};
        }
    }

    float t3[2][3];
    #pragma unroll
    for (int i = 0; i < 2; ++i) { t3[i][0] = -INFINITY; t3[i][1] = -INFINITY; t3[i][2] = -INFINITY; }

    // ---- staging: threads 0..255 copy one 16x64 bf16 S tile into LDS ----
    // write swizzle: 16B unit index ^= (row & 7)  (matches A-frag read below)
    auto stage = [&](int buf, int stile) {
        if (tid < 256) {
            int r    = tid >> 4;                 // row 0..15
            int srow = stile * 16 + r;
            uint2 v = {0u, 0u};
            if (srow < SSUP)
                v = *((const uint2*)(Sc + (size_t)srow * D_) + (tid & 15));
            int unit = (tid & 15) >> 1;          // 16B unit 0..7
            int wb   = r * 128 + (((unit ^ (r & 7)) << 4)) + ((tid & 1) * 8);
            *(uint2*)((char*)&lds[buf][0] + wb) = v;
        }
    };

    stage(0, 0);
    __syncthreads();

    for (int st = 0; st < STILES; ++st) {
        const int buf = st & 1;
        // A fragments: lane reads S[lr][kstep*32 + lg*8 .. +7] (16B, swizzled)
        const char* base = (const char*)&lds[buf][0] + lr * 128;
        short8 a0 = *(const short8*)(base + (((0 * 4 + lg) ^ (lr & 7)) << 4));
        short8 a1 = *(const short8*)(base + (((1 * 4 + lg) ^ (lr & 7)) << 4));

        const bool lastTile = (st == STILES - 1);
        #pragma unroll
        for (int i = 0; i < 2; ++i) {
            if (!qtv[i]) continue;
            f32x4 c = {0.f, 0.f, 0.f, 0.f};
            c = __builtin_amdgcn_mfma_f32_16x16x32_bf16(a0, bq[i][0], c, 0, 0, 0);
            c = __builtin_amdgcn_mfma_f32_16x16x32_bf16(a1, bq[i][1], c, 0, 0, 0);
            #pragma unroll
            for (int r = 0; r < 4; ++r) {
                float v = c[r];
                if (lastTile) {                  // mask padded support rows
                    int srow = st * 16 + lg * 4 + r;
                    v = (srow < SSUP) ? v : -INFINITY;
                }
                float m0 = fminf(v, t3[i][0]);  t3[i][0] = fmaxf(v, t3[i][0]);
                float m1 = fminf(m0, t3[i][1]); t3[i][1] = fmaxf(m0, t3[i][1]);
                t3[i][2] = fmaxf(m1, t3[i][2]);
            }
        }
        if (st + 1 < STILES) stage((st + 1) & 1, st + 1);
        __syncthreads();
    }

    // ---- merge top-3 across the 4 lane groups (same query col) ----
    float acc = 0.f;
    #pragma unroll
    for (int i = 0; i < 2; ++i) {
        if (!qtv[i]) continue;
        float t0 = t3[i][0], t1 = t3[i][1], t2 = t3[i][2];
        #pragma unroll
        for (int m = 16; m <= 32; m <<= 1) {
            float o0 = __shfl_xor(t0, m, 64);
            float o1 = __shfl_xor(t1, m, 64);
            float o2 = __shfl_xor(t2, m, 64);
            float mm, n1;
            mm = fminf(o0, t0); t0 = fmaxf(o0, t0);
            n1 = fminf(mm, t1); t1 = fmaxf(mm, t1);
            t2 = fmaxf(n1, t2);
            mm = fminf(o1, t0); t0 = fmaxf(o1, t0);
            n1 = fminf(mm, t1); t1 = fmaxf(mm, t1);
            t2 = fmaxf(n1, t2);
            mm = fminf(o2, t0); t0 = fmaxf(o2, t0);
            n1 = fminf(mm, t1); t1 = fmaxf(mm, t1);
            t2 = fmaxf(n1, t2);
        }
        if (qv[i] && lane < 16) acc += t0 + t1 + t2;  // one lane per query
    }
    #pragma unroll
    for (int m = 1; m < 64; m <<= 1) acc += __shfl_xor(acc, m, 64);
    if (lane == 0) red[wid] = acc;
    __syncthreads();
    if (tid == 0) {
        float tot = 0.f;
        #pragma unroll
        for (int i = 0; i < 8; ++i) tot += red[i];
        out[blk] = tot * (1.0f / (PQ * 3.0f));   // mean over 196 patches x k=3
    }
}

// ---------------- fp32 fallback (round-1 kernel) if ws too small ----------------
__global__ __launch_bounds__(256)
void lpc_kernel(const float* __restrict__ qfea,
                const float* __restrict__ sfea,
                float* __restrict__ out) {
    const int blk = blockIdx.x;
    const int w  = blk % WAY;
    const int qi = (blk / WAY) % NWQ;
    const int b  = blk / (WAY * NWQ);
    const int p  = threadIdx.x;
    float sum3 = 0.0f;
    if (p < PQ) {
        float qreg[D_];
        const float4* q4 = reinterpret_cast<const float4*>(
            qfea + (((size_t)b * NWQ + qi) * PQ + p) * D_);
        #pragma unroll
        for (int i = 0; i < D_ / 4; ++i) {
            float4 v = q4[i];
            qreg[4*i+0] = v.x; qreg[4*i+1] = v.y; qreg[4*i+2] = v.z; qreg[4*i+3] = v.w;
        }
        const float* sbase = sfea + ((size_t)b * WAY + w) * SSUP * D_;
        float t0 = -INFINITY, t1 = -INFINITY, t2 = -INFINITY;
        for (int s = 0; s < SSUP; ++s) {
            const float4* s4 = reinterpret_cast<const float4*>(sbase + (size_t)s * D_);
            float a0 = 0.f, a1 = 0.f, a2 = 0.f, a3 = 0.f;
            #pragma unroll
            for (int i = 0; i < D_ / 4; ++i) {
                float4 v = s4[i];
                a0 = fmaf(qreg[4*i+0], v.x, a0);
                a1 = fmaf(qreg[4*i+1], v.y, a1);
                a2 = fmaf(qreg[4*i+2], v.z, a2);
                a3 = fmaf(qreg[4*i+3], v.w, a3);
            }
            float dot = (a0 + a1) + (a2 + a3);
            float m0 = fminf(dot, t0);  t0 = fmaxf(dot, t0);
            float m1 = fminf(m0, t1);   t1 = fmaxf(m0, t1);
            t2 = fmaxf(m1, t2);
        }
        sum3 = t0 + t1 + t2;
    }
    __shared__ float red[256];
    red[threadIdx.x] = sum3;
    __syncthreads();
    #pragma unroll
    for (int off = 128; off > 0; off >>= 1) {
        if (threadIdx.x < off) red[threadIdx.x] += red[threadIdx.x + off];
        __syncthreads();
    }
    if (threadIdx.x == 0) out[blk] = red[0] * (1.0f / (PQ * 3.0f));
}

extern "C" void kernel_launch(void* const* d_in, const int* in_sizes, int n_in,
                              void* d_out, int out_size, void* d_ws, size_t ws_size,
                              hipStream_t stream) {
    const float* qf = (const float*)d_in[0];   // [2,75,196,64]
    const float* sf = (const float*)d_in[1];   // [2,5,5,196,64]
    float* out = (float*)d_out;                // [150,5]

    const size_t nQ = (size_t)B_ * NWQ * PQ * D_;           // 1,881,600
    const size_t nS = (size_t)B_ * WAY * SHOT * PQ * D_;    // 627,200
    const size_t need = (nQ + nS) * sizeof(ushort);

    const int nblk = B_ * NWQ * WAY;           // 750

    if (ws_size >= need) {
        ushort* Qb = (ushort*)d_ws;
        ushort* Sb = Qb + nQ;                  // 16B-aligned (nQ*2 % 16 == 0)
        int n4q = (int)(nQ / 4), n4s = (int)(nS / 4);
        cvt_kernel<<<(n4q + 255) / 256, 256, 0, stream>>>(qf, Qb, n4q);
        cvt_kernel<<<(n4s + 255) / 256, 256, 0, stream>>>(sf, Sb, n4s);
        lpc_mfma<<<nblk, 512, 0, stream>>>(Qb, Sb, out);
    } else {
        lpc_kernel<<<nblk, 256, 0, stream>>>(qf, sf, out);
    }
}

// Round 3
// 46.165 us; speedup vs baseline: 9.5741x; 1.3631x over previous
//
#include <hip/hip_runtime.h>

#define B_    2
#define NWQ   75
#define PQ    196
#define D_    64
#define WAY   5
#define SHOT  5
#define SSUP  (SHOT * PQ)          // 980 support patches per (b, way)
#define SPAD  992                  // padded to 62*16
#define STILES 62
#define QI_PER_BLK 3
#define QCHUNKS (NWQ / QI_PER_BLK) // 25
#define QROWS (QI_PER_BLK * PQ)    // 588
#define QTILES_BLK ((QROWS + 15) / 16)  // 37
#define NWAVE 16
#define TPW   3                    // max q-tiles per wave: ceil(37/16)

typedef __attribute__((ext_vector_type(8))) short short8;   // 8 bf16 = 4 VGPR
typedef __attribute__((ext_vector_type(4))) float f32x4;

__device__ __forceinline__ ushort f2bf(float f) {
    uint u = __builtin_bit_cast(uint, f);
    u = (u + 0x7FFFu + ((u >> 16) & 1u)) >> 16;
    return (ushort)u;
}

// fp32 -> bf16 for query (linear layout)
__global__ void cvt_q_kernel(const float* __restrict__ in, ushort* __restrict__ out, int n4) {
    int i = blockIdx.x * blockDim.x + threadIdx.x;
    if (i < n4) {
        float4 v = ((const float4*)in)[i];
        ushort4 o;
        o.x = f2bf(v.x); o.y = f2bf(v.y); o.z = f2bf(v.z); o.w = f2bf(v.w);
        ((ushort4*)out)[i] = o;
    }
}

// fp32 -> bf16 for support, padded to [2*5][992][64] with zero rows 980..991
__global__ void cvt_s_kernel(const float* __restrict__ in, ushort* __restrict__ out) {
    int i = blockIdx.x * blockDim.x + threadIdx.x;    // one 4-elem unit
    const int n = B_ * WAY * SPAD * (D_ / 4);
    if (i >= n) return;
    int d4 = i & (D_ / 4 - 1);
    int r  = (i >> 4) % SPAD;
    int p  = i / ((D_ / 4) * SPAD);                   // b*WAY + w
    ushort4 o = {0, 0, 0, 0};
    if (r < SSUP) {
        float4 v = *(const float4*)(in + ((size_t)(p * SSUP + r) * D_ + d4 * 4));
        o.x = f2bf(v.x); o.y = f2bf(v.y); o.z = f2bf(v.z); o.w = f2bf(v.w);
    }
    *(ushort4*)(out + (size_t)(p * SPAD + r) * D_ + d4 * 4) = o;
}

// Block = (b, w, chunk of 3 qi). Full 992x64 bf16 support panel staged once in
// swizzled LDS (124 KB); 16 waves each carry up to 3 query tiles (B-frags in
// regs) through a barrier-free loop over 62 support tiles:
//   2 ds_read_b128 (A frags) -> 6 MFMA -> med3-based top-3 insert (3 ops/elem).
__global__ __launch_bounds__(1024)
void lpc_full(const ushort* __restrict__ Qb, const ushort* __restrict__ Sb,
              float* __restrict__ out) {
    const int blk   = blockIdx.x;           // 0..249
    const int pair  = blk / QCHUNKS;        // b*WAY + w
    const int chunk = blk % QCHUNKS;
    const int b   = pair / WAY, w = pair % WAY;
    const int qi0 = chunk * QI_PER_BLK;
    const int tid  = threadIdx.x;
    const int wid  = tid >> 6;              // 0..15
    const int lane = tid & 63;
    const int lr   = lane & 15;             // A row within tile / C col
    const int lg   = lane >> 4;             // 0..3

    __shared__ short8 ldsv[SPAD * 8];       // 992 rows x 8 units x 16B = 126976 B
    __shared__ float  sums[4];

    if (tid < QI_PER_BLK) sums[tid] = 0.f;

    const ushort* Sc = Sb + (size_t)pair * SPAD * D_;
    const ushort* Qc = Qb + (size_t)(b * NWQ + qi0) * PQ * D_;

    // ---- stage full panel, XOR-swizzled on 16B units: unit' = u ^ (row&7) ----
    #pragma unroll
    for (int it = 0; it < 8; ++it) {
        int idx = it * 1024 + tid;          // 16B unit index, 7936 total
        if (idx < SPAD * 8) {
            int r = idx >> 3, u = idx & 7;
            short8 v = *(const short8*)(Sc + (size_t)r * D_ + u * 8);
            ldsv[(r << 3) | (u ^ (r & 7))] = v;
        }
    }

    // ---- B fragments for this wave's q-tiles (t = wid + 16*i) ----
    short8 bq[TPW][2];
    bool   tv[TPW];
    int    rw[TPW];
    bool   rv[TPW];
    #pragma unroll
    for (int i = 0; i < TPW; ++i) {
        int t = wid + NWAVE * i;
        tv[i] = (t < QTILES_BLK);
        int row = t * 16 + lr;
        rv[i] = tv[i] && (row < QROWS);
        rw[i] = row;
        int rc = rv[i] ? row : 0;
        const ushort* qrow = Qc + (size_t)rc * D_;
        if (tv[i]) {
            bq[i][0] = *(const short8*)(qrow + lg * 8);
            bq[i][1] = *(const short8*)(qrow + 32 + lg * 8);
        } else {
            bq[i][0] = short8{0,0,0,0,0,0,0,0};
            bq[i][1] = short8{0,0,0,0,0,0,0,0};
        }
    }
    __syncthreads();

    float t3[TPW][3];
    #pragma unroll
    for (int i = 0; i < TPW; ++i) {
        t3[i][0] = -__builtin_inff(); t3[i][1] = -__builtin_inff(); t3[i][2] = -__builtin_inff();
    }

    const int u0 = lg ^ (lr & 7);           // swizzled unit for k 0..31 slice
    const int u1 = (4 + lg) ^ (lr & 7);     // swizzled unit for k 32..63 slice
    const short8* lrow = ldsv + (lr << 3);  // row lr of tile 0

    // ---- main loop: tiles 0..60 need no support-row masking ----
    #pragma unroll 4
    for (int st = 0; st < STILES - 1; ++st) {
        const short8* p = lrow + st * 128;  // 16 rows * 8 units per tile
        short8 a0 = p[u0];
        short8 a1 = p[u1];
        #pragma unroll
        for (int i = 0; i < TPW; ++i) {
            if (!tv[i]) continue;
            f32x4 c = {0.f, 0.f, 0.f, 0.f};
            c = __builtin_amdgcn_mfma_f32_16x16x32_bf16(a0, bq[i][0], c, 0, 0, 0);
            c = __builtin_amdgcn_mfma_f32_16x16x32_bf16(a1, bq[i][1], c, 0, 0, 0);
            #pragma unroll
            for (int r = 0; r < 4; ++r) {
                float v = c[r];
                t3[i][2] = __builtin_amdgcn_fmed3f(v, t3[i][1], t3[i][2]);
                t3[i][1] = __builtin_amdgcn_fmed3f(v, t3[i][0], t3[i][1]);
                t3[i][0] = fmaxf(v, t3[i][0]);
            }
        }
    }
    // ---- last tile: support rows 976..991, only 976..979 (lg==0) valid ----
    {
        const short8* p = lrow + (STILES - 1) * 128;
        short8 a0 = p[u0];
        short8 a1 = p[u1];
        #pragma unroll
        for (int i = 0; i < TPW; ++i) {
            if (!tv[i]) continue;
            f32x4 c = {0.f, 0.f, 0.f, 0.f};
            c = __builtin_amdgcn_mfma_f32_16x16x32_bf16(a0, bq[i][0], c, 0, 0, 0);
            c = __builtin_amdgcn_mfma_f32_16x16x32_bf16(a1, bq[i][1], c, 0, 0, 0);
            #pragma unroll
            for (int r = 0; r < 4; ++r) {
                int srow = (STILES - 1) * 16 + lg * 4 + r;
                float v = (srow < SSUP) ? c[r] : -__builtin_inff();
                t3[i][2] = __builtin_amdgcn_fmed3f(v, t3[i][1], t3[i][2]);
                t3[i][1] = __builtin_amdgcn_fmed3f(v, t3[i][0], t3[i][1]);
                t3[i][0] = fmaxf(v, t3[i][0]);
            }
        }
    }

    // ---- merge top-3 across the 4 lane groups; reduce per qi; accumulate ----
    #pragma unroll
    for (int i = 0; i < TPW; ++i) {
        if (!tv[i]) continue;
        float t0 = t3[i][0], t1 = t3[i][1], t2 = t3[i][2];
        #pragma unroll
        for (int m = 16; m <= 32; m <<= 1) {
            float o0 = __shfl_xor(t0, m, 64);
            float o1 = __shfl_xor(t1, m, 64);
            float o2 = __shfl_xor(t2, m, 64);
            t2 = __builtin_amdgcn_fmed3f(o0, t1, t2);
            t1 = __builtin_amdgcn_fmed3f(o0, t0, t1);
            t0 = fmaxf(o0, t0);
            t2 = __builtin_amdgcn_fmed3f(o1, t1, t2);
            t1 = __builtin_amdgcn_fmed3f(o1, t0, t1);
            t0 = fmaxf(o1, t0);
            t2 = __builtin_amdgcn_fmed3f(o2, t1, t2);
            t1 = __builtin_amdgcn_fmed3f(o2, t0, t1);
            t0 = fmaxf(o2, t0);
        }
        // lanes 0..15 hold the final top-3 for row rw[i]
        float rs = (rv[i] && lane < 16) ? (t0 + t1 + t2) : 0.f;
        int qi_l = (rw[i] >= PQ) + (rw[i] >= 2 * PQ);   // 0..2 within chunk
        #pragma unroll
        for (int q = 0; q < QI_PER_BLK; ++q) {
            float vq = (qi_l == q) ? rs : 0.f;
            vq += __shfl_xor(vq, 1, 64);
            vq += __shfl_xor(vq, 2, 64);
            vq += __shfl_xor(vq, 4, 64);
            vq += __shfl_xor(vq, 8, 64);
            if (lane == 0 && vq != 0.f) atomicAdd(&sums[q], vq);
        }
    }
    __syncthreads();
    if (tid < QI_PER_BLK)
        out[(size_t)(b * NWQ + qi0 + tid) * WAY + w] = sums[tid] * (1.0f / (PQ * 3.0f));
}

// ---------------- fp32 fallback if ws too small ----------------
__global__ __launch_bounds__(256)
void lpc_kernel(const float* __restrict__ qfea,
                const float* __restrict__ sfea,
                float* __restrict__ out) {
    const int blk = blockIdx.x;
    const int w  = blk % WAY;
    const int qi = (blk / WAY) % NWQ;
    const int b  = blk / (WAY * NWQ);
    const int p  = threadIdx.x;
    float sum3 = 0.0f;
    if (p < PQ) {
        float qreg[D_];
        const float4* q4 = reinterpret_cast<const float4*>(
            qfea + (((size_t)b * NWQ + qi) * PQ + p) * D_);
        #pragma unroll
        for (int i = 0; i < D_ / 4; ++i) {
            float4 v = q4[i];
            qreg[4*i+0] = v.x; qreg[4*i+1] = v.y; qreg[4*i+2] = v.z; qreg[4*i+3] = v.w;
        }
        const float* sbase = sfea + ((size_t)b * WAY + w) * SSUP * D_;
        float t0 = -INFINITY, t1 = -INFINITY, t2 = -INFINITY;
        for (int s = 0; s < SSUP; ++s) {
            const float4* s4 = reinterpret_cast<const float4*>(sbase + (size_t)s * D_);
            float a0 = 0.f, a1 = 0.f, a2 = 0.f, a3 = 0.f;
            #pragma unroll
            for (int i = 0; i < D_ / 4; ++i) {
                float4 v = s4[i];
                a0 = fmaf(qreg[4*i+0], v.x, a0);
                a1 = fmaf(qreg[4*i+1], v.y, a1);
                a2 = fmaf(qreg[4*i+2], v.z, a2);
                a3 = fmaf(qreg[4*i+3], v.w, a3);
            }
            float dot = (a0 + a1) + (a2 + a3);
            float m0 = fminf(dot, t0);  t0 = fmaxf(dot, t0);
            float m1 = fminf(m0, t1);   t1 = fmaxf(m0, t1);
            t2 = fmaxf(m1, t2);
        }
        sum3 = t0 + t1 + t2;
    }
    __shared__ float red[256];
    red[threadIdx.x] = sum3;
    __syncthreads();
    #pragma unroll
    for (int off = 128; off > 0; off >>= 1) {
        if (threadIdx.x < off) red[threadIdx.x] += red[threadIdx.x + off];
        __syncthreads();
    }
    if (threadIdx.x == 0) out[blk] = red[0] * (1.0f / (PQ * 3.0f));
}

extern "C" void kernel_launch(void* const* d_in, const int* in_sizes, int n_in,
                              void* d_out, int out_size, void* d_ws, size_t ws_size,
                              hipStream_t stream) {
    const float* qf = (const float*)d_in[0];   // [2,75,196,64]
    const float* sf = (const float*)d_in[1];   // [2,5,5,196,64]
    float* out = (float*)d_out;                // [150,5]

    const size_t nQ = (size_t)B_ * NWQ * PQ * D_;        // 1,881,600
    const size_t nS = (size_t)B_ * WAY * SPAD * D_;      // 634,880 (padded)
    const size_t need = (nQ + nS) * sizeof(ushort);      // ~5.03 MB

    if (ws_size >= need) {
        ushort* Qb = (ushort*)d_ws;
        ushort* Sb = Qb + nQ;                 // byte offset 3,763,200 (16B aligned)
        int n4q = (int)(nQ / 4);
        int nsu = B_ * WAY * SPAD * (D_ / 4);
        cvt_q_kernel<<<(n4q + 255) / 256, 256, 0, stream>>>(qf, Qb, n4q);
        cvt_s_kernel<<<(nsu + 255) / 256, 256, 0, stream>>>(sf, Sb);
        lpc_full<<<B_ * WAY * QCHUNKS, 1024, 0, stream>>>(Qb, Sb, out);
    } else {
        lpc_kernel<<<B_ * NWQ * WAY, 256, 0, stream>>>(qf, sf, out);
    }
}

// Round 4
// 44.042 us; speedup vs baseline: 10.0355x; 1.0482x over previous
//
#include <hip/hip_runtime.h>

#define B_    2
#define NWQ   75
#define PQ    196
#define D_    64
#define WAY   5
#define SHOT  5
#define SSUP  (SHOT * PQ)          // 980 support patches per (b, way)
#define SPAD  992                  // padded to 62*16
#define STILES 62
#define QI_PER_BLK 3
#define QCHUNKS (NWQ / QI_PER_BLK) // 25
#define QROWS (QI_PER_BLK * PQ)    // 588
#define QTILES_BLK ((QROWS + 15) / 16)  // 37
#define NWAVE 16
#define TPW   3

typedef __attribute__((ext_vector_type(8))) short short8;   // 8 bf16 = 4 VGPR
typedef __attribute__((ext_vector_type(4))) float f32x4;

__device__ __forceinline__ ushort f2bf(float f) {
    uint u = __builtin_bit_cast(uint, f);
    u = (u + 0x7FFFu + ((u >> 16) & 1u)) >> 16;
    return (ushort)u;
}

__device__ __forceinline__ short8 pack8(float4 a, float4 b) {
    short8 o;
    o[0] = (short)f2bf(a.x); o[1] = (short)f2bf(a.y);
    o[2] = (short)f2bf(a.z); o[3] = (short)f2bf(a.w);
    o[4] = (short)f2bf(b.x); o[5] = (short)f2bf(b.y);
    o[6] = (short)f2bf(b.z); o[7] = (short)f2bf(b.w);
    return o;
}

// fp32 -> bf16 support panel, padded to [2*5][992][64], PRE-SWIZZLED on 16B
// units (unit' = u ^ (row&7)) so the main kernel can DMA it linearly into LDS.
__global__ __launch_bounds__(256)
void cvt_s_kernel(const float* __restrict__ in, ushort* __restrict__ out) {
    int i = blockIdx.x * blockDim.x + threadIdx.x;   // one 16B unit (8 bf16)
    const int NU = B_ * WAY * SPAD * 8;              // 79360
    if (i >= NU) return;
    int u  = i & 7;
    int r  = (i >> 3) % SPAD;
    int pr = i / (8 * SPAD);                         // b*WAY + w
    short8 o = {0,0,0,0,0,0,0,0};
    if (r < SSUP) {
        const float* src = in + ((size_t)(pr * SSUP + r) * D_ + u * 8);
        float4 f0 = *(const float4*)src;
        float4 f1 = *(const float4*)(src + 4);
        o = pack8(f0, f1);
    }
    int du = u ^ (r & 7);
    *(short8*)(out + ((size_t)(pr * SPAD + r) * 8 + du) * 8) = o;
}

// Branch-free pipelined tile loop: NT q-tile slots, register prefetch of the
// next tile's A fragments; med3-based top-3 insert (3 VALU/elem).
template<int NT>
__device__ __forceinline__ void tile_loop(const short8* __restrict__ lrow,
                                          int u0, int u1, int lg,
                                          const short8 (&bq)[TPW][2],
                                          float (&t3)[TPW][3]) {
    short8 A0 = lrow[u0];
    short8 A1 = lrow[u1];
    const short8* pn = lrow;
    #pragma unroll 2
    for (int st = 0; st < STILES - 1; ++st) {
        pn += 128;                         // next tile (16 rows x 8 units)
        short8 N0 = pn[u0];
        short8 N1 = pn[u1];
        f32x4 c[NT];
        __builtin_amdgcn_s_setprio(1);
        #pragma unroll
        for (int i = 0; i < NT; ++i) {
            f32x4 cc = {0.f, 0.f, 0.f, 0.f};
            cc = __builtin_amdgcn_mfma_f32_16x16x32_bf16(A0, bq[i][0], cc, 0, 0, 0);
            cc = __builtin_amdgcn_mfma_f32_16x16x32_bf16(A1, bq[i][1], cc, 0, 0, 0);
            c[i] = cc;
        }
        __builtin_amdgcn_s_setprio(0);
        #pragma unroll
        for (int i = 0; i < NT; ++i) {
            #pragma unroll
            for (int r = 0; r < 4; ++r) {
                float v = c[i][r];
                t3[i][2] = __builtin_amdgcn_fmed3f(v, t3[i][1], t3[i][2]);
                t3[i][1] = __builtin_amdgcn_fmed3f(v, t3[i][0], t3[i][1]);
                t3[i][0] = fmaxf(v, t3[i][0]);
            }
        }
        A0 = N0; A1 = N1;
    }
    // last tile (rows 976..991; only srow<980 valid)
    #pragma unroll
    for (int i = 0; i < NT; ++i) {
        f32x4 cc = {0.f, 0.f, 0.f, 0.f};
        cc = __builtin_amdgcn_mfma_f32_16x16x32_bf16(A0, bq[i][0], cc, 0, 0, 0);
        cc = __builtin_amdgcn_mfma_f32_16x16x32_bf16(A1, bq[i][1], cc, 0, 0, 0);
        #pragma unroll
        for (int r = 0; r < 4; ++r) {
            int srow = (STILES - 1) * 16 + lg * 4 + r;
            float v = (srow < SSUP) ? cc[r] : -__builtin_inff();
            t3[i][2] = __builtin_amdgcn_fmed3f(v, t3[i][1], t3[i][2]);
            t3[i][1] = __builtin_amdgcn_fmed3f(v, t3[i][0], t3[i][1]);
            t3[i][0] = fmaxf(v, t3[i][0]);
        }
    }
}

// Block = (b, w, chunk of 3 qi). Pre-swizzled 992x64 bf16 support panel DMA'd
// into LDS via global_load_lds (overlapped with in-kernel q fp32->bf16
// conversion); 16 waves, barrier-free pipelined MFMA + top-3 loop.
__global__ __launch_bounds__(1024)
void lpc_full(const float* __restrict__ qf, const ushort* __restrict__ Sb,
              float* __restrict__ out) {
    const int blk   = blockIdx.x;           // 0..249
    const int pair  = blk / QCHUNKS;        // b*WAY + w
    const int chunk = blk % QCHUNKS;
    const int b   = pair / WAY, w = pair % WAY;
    const int qi0 = chunk * QI_PER_BLK;
    const int tid  = threadIdx.x;
    const int wid  = tid >> 6;              // 0..15
    const int lane = tid & 63;
    const int lr   = lane & 15;
    const int lg   = lane >> 4;

    __shared__ short8 ldsv[SPAD * 8];       // 126976 B, already-swizzled layout
    __shared__ float  sums[4];

    if (tid < QI_PER_BLK) sums[tid] = 0.f;

    // ---- issue LDS DMA for the full panel (linear copy of pre-swizzled src) ----
    const char* gsrc = (const char*)(Sb + (size_t)pair * SPAD * D_);
    char* lbase = (char*)&ldsv[0];
    #pragma unroll
    for (int it = 0; it < 8; ++it) {
        int unit = it * 1024 + tid;         // lane-contiguous 16B units
        if (unit < SPAD * 8) {
#if __has_builtin(__builtin_amdgcn_global_load_lds)
            __builtin_amdgcn_global_load_lds(
                (const __attribute__((address_space(1))) unsigned int*)(gsrc + (size_t)unit * 16),
                (__attribute__((address_space(3))) unsigned int*)(lbase + (size_t)unit * 16),
                16, 0, 0);
#else
            *(short8*)(lbase + (size_t)unit * 16) = *(const short8*)(gsrc + (size_t)unit * 16);
#endif
        }
    }

    // ---- overlap: load + convert this wave's query fragments (fp32 -> bf16) ----
    const float* Qc = qf + (size_t)(b * NWQ + qi0) * PQ * D_;
    short8 bq[TPW][2];
    bool   tv[TPW];
    int    rw[TPW];
    bool   rv[TPW];
    #pragma unroll
    for (int i = 0; i < TPW; ++i) {
        int t = wid + NWAVE * i;
        tv[i] = (t < QTILES_BLK);
        int row = t * 16 + lr;
        rv[i] = tv[i] && (row < QROWS);
        rw[i] = row;
        if (tv[i]) {
            int rc = rv[i] ? row : 0;
            const float* qrow = Qc + (size_t)rc * D_;
            float4 fa = *(const float4*)(qrow + lg * 8);
            float4 fb = *(const float4*)(qrow + lg * 8 + 4);
            float4 fc = *(const float4*)(qrow + 32 + lg * 8);
            float4 fd = *(const float4*)(qrow + 32 + lg * 8 + 4);
            bq[i][0] = pack8(fa, fb);
            bq[i][1] = pack8(fc, fd);
        } else {
            bq[i][0] = short8{0,0,0,0,0,0,0,0};
            bq[i][1] = short8{0,0,0,0,0,0,0,0};
        }
    }

    float t3[TPW][3];
    #pragma unroll
    for (int i = 0; i < TPW; ++i) {
        t3[i][0] = -__builtin_inff(); t3[i][1] = -__builtin_inff(); t3[i][2] = -__builtin_inff();
    }

    asm volatile("s_waitcnt vmcnt(0)" ::: "memory");
    __syncthreads();

    const int u0 = lg ^ (lr & 7);
    const int u1 = (4 + lg) ^ (lr & 7);
    const short8* lrow = ldsv + (lr << 3);

    if (wid < QTILES_BLK - 2 * NWAVE)       // waves 0..4 own a third q-tile
        tile_loop<3>(lrow, u0, u1, lg, bq, t3);
    else
        tile_loop<2>(lrow, u0, u1, lg, bq, t3);

    // ---- merge top-3 across the 4 lane groups; reduce per qi ----
    #pragma unroll
    for (int i = 0; i < TPW; ++i) {
        if (!tv[i]) continue;
        float t0 = t3[i][0], t1 = t3[i][1], t2 = t3[i][2];
        #pragma unroll
        for (int m = 16; m <= 32; m <<= 1) {
            float o0 = __shfl_xor(t0, m, 64);
            float o1 = __shfl_xor(t1, m, 64);
            float o2 = __shfl_xor(t2, m, 64);
            t2 = __builtin_amdgcn_fmed3f(o0, t1, t2);
            t1 = __builtin_amdgcn_fmed3f(o0, t0, t1);
            t0 = fmaxf(o0, t0);
            t2 = __builtin_amdgcn_fmed3f(o1, t1, t2);
            t1 = __builtin_amdgcn_fmed3f(o1, t0, t1);
            t0 = fmaxf(o1, t0);
            t2 = __builtin_amdgcn_fmed3f(o2, t1, t2);
            t1 = __builtin_amdgcn_fmed3f(o2, t0, t1);
            t0 = fmaxf(o2, t0);
        }
        float rs = (rv[i] && lane < 16) ? (t0 + t1 + t2) : 0.f;
        int qi_l = (rw[i] >= PQ) + (rw[i] >= 2 * PQ);
        #pragma unroll
        for (int q = 0; q < QI_PER_BLK; ++q) {
            float vq = (qi_l == q) ? rs : 0.f;
            vq += __shfl_xor(vq, 1, 64);
            vq += __shfl_xor(vq, 2, 64);
            vq += __shfl_xor(vq, 4, 64);
            vq += __shfl_xor(vq, 8, 64);
            if (lane == 0 && vq != 0.f) atomicAdd(&sums[q], vq);
        }
    }
    __syncthreads();
    if (tid < QI_PER_BLK)
        out[(size_t)(b * NWQ + qi0 + tid) * WAY + w] = sums[tid] * (1.0f / (PQ * 3.0f));
}

// ---------------- fp32 fallback if ws too small ----------------
__global__ __launch_bounds__(256)
void lpc_kernel(const float* __restrict__ qfea,
                const float* __restrict__ sfea,
                float* __restrict__ out) {
    const int blk = blockIdx.x;
    const int w  = blk % WAY;
    const int qi = (blk / WAY) % NWQ;
    const int b  = blk / (WAY * NWQ);
    const int p  = threadIdx.x;
    float sum3 = 0.0f;
    if (p < PQ) {
        float qreg[D_];
        const float4* q4 = reinterpret_cast<const float4*>(
            qfea + (((size_t)b * NWQ + qi) * PQ + p) * D_);
        #pragma unroll
        for (int i = 0; i < D_ / 4; ++i) {
            float4 v = q4[i];
            qreg[4*i+0] = v.x; qreg[4*i+1] = v.y; qreg[4*i+2] = v.z; qreg[4*i+3] = v.w;
        }
        const float* sbase = sfea + ((size_t)b * WAY + w) * SSUP * D_;
        float t0 = -INFINITY, t1 = -INFINITY, t2 = -INFINITY;
        for (int s = 0; s < SSUP; ++s) {
            const float4* s4 = reinterpret_cast<const float4*>(sbase + (size_t)s * D_);
            float a0 = 0.f, a1 = 0.f, a2 = 0.f, a3 = 0.f;
            #pragma unroll
            for (int i = 0; i < D_ / 4; ++i) {
                float4 v = s4[i];
                a0 = fmaf(qreg[4*i+0], v.x, a0);
                a1 = fmaf(qreg[4*i+1], v.y, a1);
                a2 = fmaf(qreg[4*i+2], v.z, a2);
                a3 = fmaf(qreg[4*i+3], v.w, a3);
            }
            float dot = (a0 + a1) + (a2 + a3);
            float m0 = fminf(dot, t0);  t0 = fmaxf(dot, t0);
            float m1 = fminf(m0, t1);   t1 = fmaxf(m0, t1);
            t2 = fmaxf(m1, t2);
        }
        sum3 = t0 + t1 + t2;
    }
    __shared__ float red[256];
    red[threadIdx.x] = sum3;
    __syncthreads();
    #pragma unroll
    for (int off = 128; off > 0; off >>= 1) {
        if (threadIdx.x < off) red[threadIdx.x] += red[threadIdx.x + off];
        __syncthreads();
    }
    if (threadIdx.x == 0) out[blk] = red[0] * (1.0f / (PQ * 3.0f));
}

extern "C" void kernel_launch(void* const* d_in, const int* in_sizes, int n_in,
                              void* d_out, int out_size, void* d_ws, size_t ws_size,
                              hipStream_t stream) {
    const float* qf = (const float*)d_in[0];   // [2,75,196,64]
    const float* sf = (const float*)d_in[1];   // [2,5,5,196,64]
    float* out = (float*)d_out;                // [150,5]

    const size_t nS = (size_t)B_ * WAY * SPAD * D_;      // 634,880 (padded)
    const size_t need = nS * sizeof(ushort);             // ~1.27 MB

    if (ws_size >= need) {
        ushort* Sb = (ushort*)d_ws;
        const int NU = B_ * WAY * SPAD * 8;              // 79360 units
        cvt_s_kernel<<<(NU + 255) / 256, 256, 0, stream>>>(sf, Sb);
        lpc_full<<<B_ * WAY * QCHUNKS, 1024, 0, stream>>>(qf, Sb, out);
    } else {
        lpc_kernel<<<B_ * NWQ * WAY, 256, 0, stream>>>(qf, sf, out);
    }
}